// Round 6
// baseline (224.414 us; speedup 1.0000x reference)
//
#include <hip/hip_runtime.h>

// Inception Temporal Layer — 3 causal VALID conv1d + leaky_relu(0.01).
// x[8192][512][4] f32; w1[16][4][6]; w2[16][16][4]; w3[16][16][13]; out[8192][3][48][16].
// Cone: o3[t<48] <- even o2[0..142] <- o1[0..148] <- x[0..458].
//
// Round 6: TWO waves share one row's LDS slice (14,336 B) -> still 11 blocks/CU
// but 22 waves/CU (2x round-5 occupancy). Balanced split:
//   w0: stage1 t=0..63        | stage2A j=0..63 (+scale1 store) | stage3 co 0..7
//   w1: stage1 t=64..151      | stage2B j=64..142 even          | stage3 co 8..15
// Two uniform __syncthreads() between stages. Per-output FMA order unchanged
// from round 5 (bit-identical output).
// Packed fp32 (v_pk_fma_f32) halves issue slots (FLOP rate unchanged).

typedef float v2f __attribute__((ext_vector_type(2)));

__device__ __forceinline__ v2f fma2(v2f a, v2f b, v2f c) {
    return __builtin_elementwise_fma(a, b, c);
}

// ws float layout:
//   [0..383]     w1t[(ch*6+k)*16+co]
//   [384..1407]  w2t[(ci*4+k)*16+co]
//   [1408..4735] w3t[(ci*13+k)*16+co]
//   [4736..4751] b1   [4752..4767] b2   [4768..4783] b3
__global__ void wtrans_kernel(const float* __restrict__ w1, const float* __restrict__ b1,
                              const float* __restrict__ w2, const float* __restrict__ b2,
                              const float* __restrict__ w3, const float* __restrict__ b3,
                              float* __restrict__ ws) {
    const int tid = threadIdx.x;
    for (int t = tid; t < 384; t += 256)  { int co = t / 24,  r = t % 24;  ws[r * 16 + co] = w1[t]; }
    for (int t = tid; t < 1024; t += 256) { int co = t >> 6,  r = t & 63;  ws[384 + r * 16 + co] = w2[t]; }
    for (int t = tid; t < 3328; t += 256) { int co = t / 208, r = t % 208; ws[1408 + r * 16 + co] = w3[t]; }
    if (tid < 16) { ws[4736 + tid] = b1[tid]; ws[4752 + tid] = b2[tid]; ws[4768 + tid] = b3[tid]; }
}

__device__ __forceinline__ void act16(const v2f acc[8], float av[16]) {
    #pragma unroll
    for (int p = 0; p < 8; ++p) {
        av[2 * p]     = fmaxf(acc[p].x, 0.01f * acc[p].x);
        av[2 * p + 1] = fmaxf(acc[p].y, 0.01f * acc[p].y);
    }
}

__global__ __launch_bounds__(128, 5) void itl_kernel(
    const float* __restrict__ x,
    const float* __restrict__ wt,
    float* __restrict__ out)
{
    __shared__ float o1[16 * 152];   // o1[ci*152 + t], t valid 0..151
    __shared__ float o2e[16 * 72];   // even o2 rows: o2e[ci*72 + j/2]

    const int lane = threadIdx.x & 63;
    const int wv   = threadIdx.x >> 6;      // 2 waves share one row
    const int n    = blockIdx.x;

    const float4* x4  = reinterpret_cast<const float4*>(x) + (size_t)n * 512;
    const v2f* w1t = reinterpret_cast<const v2f*>(wt);            // [(ch*6+k)*8 + p]
    const v2f* w2t = reinterpret_cast<const v2f*>(wt + 384);      // [(ci*4+k)*8 + p]
    const v2f* w3t = reinterpret_cast<const v2f*>(wt + 1408);     // [(ci*13+k)*8 + p]
    const v2f* bs  = reinterpret_cast<const v2f*>(wt + 4736);     // b1:0..7 b2:8..15 b3:16..23
    float* outn = out + (size_t)n * 2304;

    // ---------------- stage 1 ----------------------------------------------------
    // w0: t = lane (chunk0).  w1: t = 64+lane (chunk1), t = 128+lane, lane<24 (chunk2)
    {
        const int nch   = wv ? 2 : 1;
        const int tbase = wv ? 64 : 0;
        for (int c = 0; c < nch; ++c) {
            const int t = tbase + 64 * c + lane;
            if (t < 152) {
                float xv[24];                             // x[3t..3t+5][0..3]
                #pragma unroll
                for (int k = 0; k < 6; ++k)
                    *reinterpret_cast<float4*>(&xv[4 * k]) = x4[3 * t + k];
                v2f acc[8];
                #pragma unroll
                for (int p = 0; p < 8; ++p) acc[p] = bs[p];
                #pragma unroll
                for (int ch = 0; ch < 4; ++ch)
                    #pragma unroll
                    for (int k = 0; k < 6; ++k) {
                        const float xs = xv[4 * k + ch];
                        const v2f xs2 = {xs, xs};
                        #pragma unroll
                        for (int p = 0; p < 8; ++p)
                            acc[p] = fma2(xs2, w1t[(ch * 6 + k) * 8 + p], acc[p]);
                    }
                float av[16];
                act16(acc, av);
                #pragma unroll
                for (int co = 0; co < 16; ++co) o1[co * 152 + t] = av[co];
                if (t < 48) {                             // scale 0 (only w0 chunk0)
                    float4* d = reinterpret_cast<float4*>(outn + t * 16);
                    #pragma unroll
                    for (int q = 0; q < 4; ++q)
                        d[q] = *reinterpret_cast<const float4*>(&av[4 * q]);
                }
            }
        }
    }
    __syncthreads();

    // ---------------- stage 2 ----------------------------------------------------
    if (wv == 0) {
        // chunk A: j = lane (0..63); even -> o2e slots 0..31; j<48 -> scale 1
        const int j = lane;
        v2f acc[8];
        #pragma unroll
        for (int p = 0; p < 8; ++p) acc[p] = bs[8 + p];
        #pragma unroll 2
        for (int ci = 0; ci < 16; ++ci)
            #pragma unroll
            for (int k = 0; k < 4; ++k) {
                const float xs = o1[ci * 152 + j + 2 * k];        // <= 69
                const v2f xs2 = {xs, xs};
                #pragma unroll
                for (int p = 0; p < 8; ++p)
                    acc[p] = fma2(xs2, w2t[(ci * 4 + k) * 8 + p], acc[p]);
            }
        float av[16];
        act16(acc, av);
        if ((j & 1) == 0) {
            #pragma unroll
            for (int co = 0; co < 16; ++co) o2e[co * 72 + (j >> 1)] = av[co];
        }
        if (j < 48) {
            float4* d = reinterpret_cast<float4*>(outn + 768 + j * 16);  // scale 1
            #pragma unroll
            for (int q = 0; q < 4; ++q)
                d[q] = *reinterpret_cast<const float4*>(&av[4 * q]);
        }
    } else if (lane < 40) {
        // chunk B: j = 64 + 2*lane (64..142 even) -> o2e slots 32..71
        const int j = 64 + 2 * lane;
        v2f acc[8];
        #pragma unroll
        for (int p = 0; p < 8; ++p) acc[p] = bs[8 + p];
        #pragma unroll 2
        for (int ci = 0; ci < 16; ++ci)
            #pragma unroll
            for (int k = 0; k < 4; ++k) {
                const float xs = o1[ci * 152 + j + 2 * k];        // <= 148
                const v2f xs2 = {xs, xs};
                #pragma unroll
                for (int p = 0; p < 8; ++p)
                    acc[p] = fma2(xs2, w2t[(ci * 4 + k) * 8 + p], acc[p]);
            }
        float av[16];
        act16(acc, av);
        #pragma unroll
        for (int co = 0; co < 16; ++co) o2e[co * 72 + (j >> 1)] = av[co];
    }
    __syncthreads();

    // ---------------- stage 3: t = lane < 48, each wave owns 8 output channels ---
    if (lane < 48) {
        const int t = lane;
        const int pb = wv * 4;                            // v2f pairs: co 8*wv .. 8*wv+7
        v2f acc[4];
        #pragma unroll
        for (int p = 0; p < 4; ++p) acc[p] = bs[16 + pb + p];
        #pragma unroll 2
        for (int ci = 0; ci < 16; ++ci)
            #pragma unroll
            for (int k = 0; k < 13; ++k) {
                const float xs = o2e[ci * 72 + t + 2 * k];        // slot <= 71
                const v2f xs2 = {xs, xs};
                #pragma unroll
                for (int p = 0; p < 4; ++p)
                    acc[p] = fma2(xs2, w3t[(ci * 13 + k) * 8 + pb + p], acc[p]);
            }
        float av[8];
        #pragma unroll
        for (int p = 0; p < 4; ++p) {
            av[2 * p]     = fmaxf(acc[p].x, 0.01f * acc[p].x);
            av[2 * p + 1] = fmaxf(acc[p].y, 0.01f * acc[p].y);
        }
        float4* d = reinterpret_cast<float4*>(outn + 1536 + t * 16 + 8 * wv);  // scale 2
        d[0] = *reinterpret_cast<const float4*>(&av[0]);
        d[1] = *reinterpret_cast<const float4*>(&av[4]);
    }
}

extern "C" void kernel_launch(void* const* d_in, const int* in_sizes, int n_in,
                              void* d_out, int out_size, void* d_ws, size_t ws_size,
                              hipStream_t stream) {
    const float* x  = (const float*)d_in[0];
    const float* w1 = (const float*)d_in[1];
    const float* b1 = (const float*)d_in[2];
    const float* w2 = (const float*)d_in[3];
    const float* b2 = (const float*)d_in[4];
    const float* w3 = (const float*)d_in[5];
    const float* b3 = (const float*)d_in[6];
    float* out = (float*)d_out;
    float* ws  = (float*)d_ws;                        // needs 4784 floats = 19,136 B

    wtrans_kernel<<<1, 256, 0, stream>>>(w1, b1, w2, b2, w3, b3, ws);
    itl_kernel<<<8192, 128, 0, stream>>>(x, ws, out); // 1 row / block, 2 waves share it
}

// Round 7
// 221.443 us; speedup vs baseline: 1.0134x; 1.0134x over previous
//
#include <hip/hip_runtime.h>

// Inception Temporal Layer — 3 causal VALID conv1d + leaky_relu(0.01).
// x[8192][512][4] f32; w1[16][4][6]; w2[16][16][4]; w3[16][16][13]; out[8192][3][48][16].
// Cone: o3[t<48] <- even o2[0..142] <- o1[0..148] <- x[0..458].
//
// Round 7 = round 6 structure (2 waves share one row's 14,336B LDS slice ->
// 11 blocks/CU = 22 waves/CU) with the spill fixed:
//  - __launch_bounds__(128, 2): round 6's (128,5) forced VGPR 68->44 and
//    spilled xv/acc to scratch (VALUBusy 50->25%, dur 107->224us).
//  - stage 1 fully unrolled per wave (no runtime-bound loop).
// Work split:  w0: stage1 t=0..63 (+scale0) | stage2 j=0..63 (+scale1) | stage3 co 0..7
//              w1: stage1 t=64..151         | stage2 j=64..142 even    | stage3 co 8..15
// Accumulation order per output unchanged since round 5 -> bit-identical.

typedef float v2f __attribute__((ext_vector_type(2)));

__device__ __forceinline__ v2f fma2(v2f a, v2f b, v2f c) {
    return __builtin_elementwise_fma(a, b, c);
}

// ws float layout:
//   [0..383]     w1t[(ch*6+k)*16+co]
//   [384..1407]  w2t[(ci*4+k)*16+co]
//   [1408..4735] w3t[(ci*13+k)*16+co]
//   [4736..4751] b1   [4752..4767] b2   [4768..4783] b3
__global__ void wtrans_kernel(const float* __restrict__ w1, const float* __restrict__ b1,
                              const float* __restrict__ w2, const float* __restrict__ b2,
                              const float* __restrict__ w3, const float* __restrict__ b3,
                              float* __restrict__ ws) {
    const int tid = threadIdx.x;
    for (int t = tid; t < 384; t += 256)  { int co = t / 24,  r = t % 24;  ws[r * 16 + co] = w1[t]; }
    for (int t = tid; t < 1024; t += 256) { int co = t >> 6,  r = t & 63;  ws[384 + r * 16 + co] = w2[t]; }
    for (int t = tid; t < 3328; t += 256) { int co = t / 208, r = t % 208; ws[1408 + r * 16 + co] = w3[t]; }
    if (tid < 16) { ws[4736 + tid] = b1[tid]; ws[4752 + tid] = b2[tid]; ws[4768 + tid] = b3[tid]; }
}

__device__ __forceinline__ void act16(const v2f acc[8], float av[16]) {
    #pragma unroll
    for (int p = 0; p < 8; ++p) {
        av[2 * p]     = fmaxf(acc[p].x, 0.01f * acc[p].x);
        av[2 * p + 1] = fmaxf(acc[p].y, 0.01f * acc[p].y);
    }
}

// one stage-1 position t: read x[3t..3t+5][:], produce o1[:, t] (+ scale-0 row)
__device__ __forceinline__ void stage1_pos(int t, const float4* __restrict__ x4,
                                           const v2f* __restrict__ w1t,
                                           const v2f* __restrict__ bs,
                                           float* __restrict__ o1,
                                           float* __restrict__ outn) {
    float xv[24];                             // x[3t..3t+5][0..3]
    #pragma unroll
    for (int k = 0; k < 6; ++k)
        *reinterpret_cast<float4*>(&xv[4 * k]) = x4[3 * t + k];
    v2f acc[8];
    #pragma unroll
    for (int p = 0; p < 8; ++p) acc[p] = bs[p];
    #pragma unroll
    for (int ch = 0; ch < 4; ++ch)
        #pragma unroll
        for (int k = 0; k < 6; ++k) {
            const float xs = xv[4 * k + ch];
            const v2f xs2 = {xs, xs};
            #pragma unroll
            for (int p = 0; p < 8; ++p)
                acc[p] = fma2(xs2, w1t[(ch * 6 + k) * 8 + p], acc[p]);
        }
    float av[16];
    act16(acc, av);
    #pragma unroll
    for (int co = 0; co < 16; ++co) o1[co * 152 + t] = av[co];
    if (t < 48) {                             // scale 0
        float4* d = reinterpret_cast<float4*>(outn + t * 16);
        #pragma unroll
        for (int q = 0; q < 4; ++q)
            d[q] = *reinterpret_cast<const float4*>(&av[4 * q]);
    }
}

// one stage-2 position j: read o1[:, j..j+6], produce 16 channels
__device__ __forceinline__ void stage2_pos(int j, const float* __restrict__ o1,
                                           const v2f* __restrict__ w2t,
                                           const v2f* __restrict__ bs,
                                           float av[16]) {
    v2f acc[8];
    #pragma unroll
    for (int p = 0; p < 8; ++p) acc[p] = bs[8 + p];
    #pragma unroll 2
    for (int ci = 0; ci < 16; ++ci)
        #pragma unroll
        for (int k = 0; k < 4; ++k) {
            const float xs = o1[ci * 152 + j + 2 * k];
            const v2f xs2 = {xs, xs};
            #pragma unroll
            for (int p = 0; p < 8; ++p)
                acc[p] = fma2(xs2, w2t[(ci * 4 + k) * 8 + p], acc[p]);
        }
    act16(acc, av);
}

__global__ __launch_bounds__(128, 2) void itl_kernel(
    const float* __restrict__ x,
    const float* __restrict__ wt,
    float* __restrict__ out)
{
    __shared__ float o1[16 * 152];   // o1[ci*152 + t], t valid 0..151
    __shared__ float o2e[16 * 72];   // even o2 rows: o2e[ci*72 + j/2]

    const int lane = threadIdx.x & 63;
    const int wv   = threadIdx.x >> 6;      // 2 waves share one row
    const int n    = blockIdx.x;

    const float4* x4  = reinterpret_cast<const float4*>(x) + (size_t)n * 512;
    const v2f* w1t = reinterpret_cast<const v2f*>(wt);            // [(ch*6+k)*8 + p]
    const v2f* w2t = reinterpret_cast<const v2f*>(wt + 384);      // [(ci*4+k)*8 + p]
    const v2f* w3t = reinterpret_cast<const v2f*>(wt + 1408);     // [(ci*13+k)*8 + p]
    const v2f* bs  = reinterpret_cast<const v2f*>(wt + 4736);     // b1:0..7 b2:8..15 b3:16..23
    float* outn = out + (size_t)n * 2304;

    // ---------------- stage 1 ----------------------------------------------------
    if (wv == 0) {
        stage1_pos(lane, x4, w1t, bs, o1, outn);
    } else {
        stage1_pos(64 + lane, x4, w1t, bs, o1, outn);
        if (lane < 24) stage1_pos(128 + lane, x4, w1t, bs, o1, outn);
    }
    __syncthreads();

    // ---------------- stage 2 ----------------------------------------------------
    if (wv == 0) {
        // chunk A: j = lane (0..63); even -> o2e slots 0..31; j<48 -> scale 1
        const int j = lane;
        float av[16];
        stage2_pos(j, o1, w2t, bs, av);
        if ((j & 1) == 0) {
            #pragma unroll
            for (int co = 0; co < 16; ++co) o2e[co * 72 + (j >> 1)] = av[co];
        }
        if (j < 48) {
            float4* d = reinterpret_cast<float4*>(outn + 768 + j * 16);  // scale 1
            #pragma unroll
            for (int q = 0; q < 4; ++q)
                d[q] = *reinterpret_cast<const float4*>(&av[4 * q]);
        }
    } else if (lane < 40) {
        // chunk B: j = 64 + 2*lane (64..142 even) -> o2e slots 32..71
        const int j = 64 + 2 * lane;
        float av[16];
        stage2_pos(j, o1, w2t, bs, av);
        #pragma unroll
        for (int co = 0; co < 16; ++co) o2e[co * 72 + (j >> 1)] = av[co];
    }
    __syncthreads();

    // ---------------- stage 3: t = lane < 48, each wave owns 8 output channels ---
    if (lane < 48) {
        const int t = lane;
        const int pb = wv * 4;                            // v2f pairs: co 8*wv .. 8*wv+7
        v2f acc[4];
        #pragma unroll
        for (int p = 0; p < 4; ++p) acc[p] = bs[16 + pb + p];
        #pragma unroll 2
        for (int ci = 0; ci < 16; ++ci)
            #pragma unroll
            for (int k = 0; k < 13; ++k) {
                const float xs = o2e[ci * 72 + t + 2 * k];        // slot <= 71
                const v2f xs2 = {xs, xs};
                #pragma unroll
                for (int p = 0; p < 4; ++p)
                    acc[p] = fma2(xs2, w3t[(ci * 13 + k) * 8 + pb + p], acc[p]);
            }
        float av[8];
        #pragma unroll
        for (int p = 0; p < 4; ++p) {
            av[2 * p]     = fmaxf(acc[p].x, 0.01f * acc[p].x);
            av[2 * p + 1] = fmaxf(acc[p].y, 0.01f * acc[p].y);
        }
        float4* d = reinterpret_cast<float4*>(outn + 1536 + t * 16 + 8 * wv);  // scale 2
        d[0] = *reinterpret_cast<const float4*>(&av[0]);
        d[1] = *reinterpret_cast<const float4*>(&av[4]);
    }
}

extern "C" void kernel_launch(void* const* d_in, const int* in_sizes, int n_in,
                              void* d_out, int out_size, void* d_ws, size_t ws_size,
                              hipStream_t stream) {
    const float* x  = (const float*)d_in[0];
    const float* w1 = (const float*)d_in[1];
    const float* b1 = (const float*)d_in[2];
    const float* w2 = (const float*)d_in[3];
    const float* b2 = (const float*)d_in[4];
    const float* w3 = (const float*)d_in[5];
    const float* b3 = (const float*)d_in[6];
    float* out = (float*)d_out;
    float* ws  = (float*)d_ws;                        // needs 4784 floats = 19,136 B

    wtrans_kernel<<<1, 256, 0, stream>>>(w1, b1, w2, b2, w3, b3, ws);
    itl_kernel<<<8192, 128, 0, stream>>>(x, ws, out); // 1 row / block, 2 waves share it
}

// Round 8
// 34.163 us; speedup vs baseline: 6.5690x; 6.4820x over previous
//
#include <hip/hip_runtime.h>

// Inception Temporal Layer — 3 causal VALID conv1d + leaky_relu(0.01).
// x[8192][512][4] f32; w1[16][4][6]; w2[16][16][4]; w3[16][16][13]; out[8192][3][48][16].
// Cone: o3[t<48] <- even o2[0..142] <- o1[0..148] <- x[0..458].
//
// Round 8: MFMA (mfma_f32_16x16x32_bf16, fp32 accum) for all 3 stages.
// Per row: stage1 10 tiles x 1 MFMA (K=24 pad 32), stage2 9 x 2 (K=64),
// stage3 3 x 7 (K=208 pad 224) = 49 MFMA (vs ~3264 pk-fma in round 5).
// im2col K-order k = kk*16 + ci  =>  A-frag (lane: row=l&15, k=8*(l>>4)+e)
// reads 8 consecutive ci from one LDS row = ONE ds_read_b128 per MFMA.
// Weights pre-packed frag-ready (bf16 pairs) in d_ws; K-pad rows zeroed so
// garbage A x zero B = 0. o1/o2even in LDS as bf16 [t][24] (48B rows: 16B
// aligned, <=2-way banks). One wave per row, no cross-wave coupling.
// A-frag:  row = l&15, k = 8*(l>>4)+e (e ascending, 2 per VGPR lo/hi)
// B-frag:  col = l&15, same k mapping
// D-frag:  col = l&15, row = 4*(l>>4)+r   [m89-verified]

typedef __attribute__((ext_vector_type(8))) short bf16x8;
typedef __attribute__((ext_vector_type(4))) float f32x4;
typedef __attribute__((ext_vector_type(4))) unsigned int u32x4;

union FragU { u32x4 u; bf16x8 b; };

__device__ __forceinline__ unsigned short f2bf(float f) {   // RTN-even
    unsigned int u = __builtin_bit_cast(unsigned int, f);
    u += 0x7FFFu + ((u >> 16) & 1u);
    return (unsigned short)(u >> 16);
}
__device__ __forceinline__ unsigned int pack2bf(float lo, float hi) {
    return (unsigned int)f2bf(lo) | ((unsigned int)f2bf(hi) << 16);
}

// d_ws u32 layout (frag-ready B, bf16 pairs; pair kp holds k=2kp lo, 2kp+1 hi):
//   [0..255]     B1[(kp)*16+co], k = kk*4+ch  (K=24, kp>=12 -> 0)
//   [256..767]   B2[(kp)*16+co], k = kk*16+ci (K=64)
//   [768..2559]  B3[(kp)*16+co], k = kk*16+ci (K=208, kk=13 -> 0)
//   f32: [2560..2575] b1, [2576..2591] b2, [2592..2607] b3
__global__ void wtrans_kernel(const float* __restrict__ w1, const float* __restrict__ b1,
                              const float* __restrict__ w2, const float* __restrict__ b2,
                              const float* __restrict__ w3, const float* __restrict__ b3,
                              unsigned int* __restrict__ ws) {
    const int tid = threadIdx.x;                    // 256 threads
    if (tid < 256) {                                // B1: k = kk*4 + ch
        int kp = tid >> 4, co = tid & 15;
        int k0 = 2 * kp, k1 = k0 + 1;
        float v0 = (k0 < 24) ? w1[co * 24 + (k0 & 3) * 6 + (k0 >> 2)] : 0.f;
        float v1 = (k1 < 24) ? w1[co * 24 + (k1 & 3) * 6 + (k1 >> 2)] : 0.f;
        ws[tid] = pack2bf(v0, v1);
    }
    for (int p = tid; p < 512; p += 256) {          // B2: k = kk*16 + ci
        int kp = p >> 4, co = p & 15;
        int k0 = 2 * kp, ci0 = k0 & 15, kk = k0 >> 4;
        ws[256 + p] = pack2bf(w2[co * 64 + ci0 * 4 + kk],
                              w2[co * 64 + (ci0 + 1) * 4 + kk]);
    }
    for (int p = tid; p < 1792; p += 256) {         // B3: k = kk*16 + ci
        int kp = p >> 4, co = p & 15;
        int k0 = 2 * kp, ci0 = k0 & 15, kk = k0 >> 4;
        float v0 = (kk < 13) ? w3[co * 208 + ci0 * 13 + kk] : 0.f;
        float v1 = (kk < 13) ? w3[co * 208 + (ci0 + 1) * 13 + kk] : 0.f;
        ws[768 + p] = pack2bf(v0, v1);
    }
    float* wf = (float*)ws;
    if (tid < 16) { wf[2560 + tid] = b1[tid]; wf[2576 + tid] = b2[tid]; wf[2592 + tid] = b3[tid]; }
}

__global__ __launch_bounds__(64, 4) void itl_kernel(
    const float* __restrict__ x,
    const unsigned int* __restrict__ wt,
    float* __restrict__ out)
{
    __shared__ __align__(16) unsigned short o1b[160 * 24];  // bf16 o1[t][ci], 48B rows
    __shared__ __align__(16) unsigned short o2e[76 * 24];   // bf16 even-o2 [slot][ci]

    const int lane = threadIdx.x;        // 0..63, one wave per row
    const int n    = blockIdx.x;
    const int co   = lane & 15;          // A/D row-col index (l&15)
    const int g    = lane >> 4;          // 0..3
    const int gh   = g >> 1;             // (l>>5)
    const int cib  = 8 * (g & 1);        // ci base of this lane's A elements

    const float4* x4 = reinterpret_cast<const float4*>(x) + (size_t)n * 512;
    const float* wf  = (const float*)wt;
    float* outn = out + (size_t)n * 2304;

    // zero the o2e pad rows 72..75 (read under zero-B k-padding in stage 3)
    if (lane < 48) ((unsigned int*)o2e)[72 * 12 + lane] = 0u;

    // ---------------- stage 1: 10 tiles, K=24 pad 32 ---------------------------
    {
        FragU b1f;
        #pragma unroll
        for (int p = 0; p < 4; ++p) b1f.u[p] = wt[(4 * g + p) * 16 + co];
        const float bias1 = wf[2560 + co];
        #pragma unroll
        for (int ti = 0; ti < 10; ++ti) {
            const int j0 = 16 * ti;
            const int t  = j0 + co;              // A row; x window 3t + (2g, 2g+1)
            float4 xa = x4[3 * t + 2 * g];
            float4 xb = x4[3 * t + 2 * g + 1];   // max idx 3*159+7 = 484 < 512
            FragU a;
            a.u[0] = pack2bf(xa.x, xa.y);
            a.u[1] = pack2bf(xa.z, xa.w);
            a.u[2] = pack2bf(xb.x, xb.y);
            a.u[3] = pack2bf(xb.z, xb.w);
            f32x4 acc = {bias1, bias1, bias1, bias1};
            acc = __builtin_amdgcn_mfma_f32_16x16x32_bf16(a.b, b1f.b, acc, 0, 0, 0);
            const int tD = j0 + 4 * g;           // D row = 4*(l>>4)+r
            #pragma unroll
            for (int r = 0; r < 4; ++r) {
                float v = acc[r]; v = fmaxf(v, 0.01f * v);
                o1b[(tD + r) * 24 + co] = f2bf(v);          // rows <= 159 < 160
                if (ti < 3) outn[(tD + r) * 16 + co] = v;   // scale 0, t<48
            }
        }
    }
    __syncthreads();

    // ---------------- stage 2: 9 tiles x 2 k-steps, K=64 -----------------------
    {
        FragU b2f[2];
        #pragma unroll
        for (int kb = 0; kb < 2; ++kb)
            #pragma unroll
            for (int p = 0; p < 4; ++p)
                b2f[kb].u[p] = wt[256 + (16 * kb + 4 * g + p) * 16 + co];
        const float bias2 = wf[2576 + co];
        #pragma unroll
        for (int ti = 0; ti < 9; ++ti) {
            const int j0 = 16 * ti;
            f32x4 acc = {bias2, bias2, bias2, bias2};
            #pragma unroll
            for (int kb = 0; kb < 2; ++kb) {
                const int row = j0 + co + 2 * (2 * kb + gh);    // <= 149
                FragU a; a.u = *(const u32x4*)&o1b[row * 24 + cib];
                acc = __builtin_amdgcn_mfma_f32_16x16x32_bf16(a.b, b2f[kb].b, acc, 0, 0, 0);
            }
            const int jD = j0 + 4 * g;
            #pragma unroll
            for (int r = 0; r < 4; ++r) {
                float v = acc[r]; v = fmaxf(v, 0.01f * v);
                if ((r & 1) == 0) o2e[((jD + r) >> 1) * 24 + co] = f2bf(v);  // even j
                if (ti < 3) outn[768 + (jD + r) * 16 + co] = v;  // scale 1, j<48
            }
        }
    }
    __syncthreads();

    // ---------------- stage 3: 3 tiles x 7 k-steps, K=208 pad 224 --------------
    {
        FragU b3f[7];
        #pragma unroll
        for (int kb = 0; kb < 7; ++kb)
            #pragma unroll
            for (int p = 0; p < 4; ++p)
                b3f[kb].u[p] = wt[768 + (16 * kb + 4 * g + p) * 16 + co];
        const float bias3 = wf[2592 + co];
        #pragma unroll
        for (int ti = 0; ti < 3; ++ti) {
            const int t0 = 16 * ti;
            f32x4 acc = {bias3, bias3, bias3, bias3};
            #pragma unroll
            for (int kb = 0; kb < 7; ++kb) {
                const int row = t0 + co + 2 * (2 * kb + gh);    // <= 73 < 76
                FragU a; a.u = *(const u32x4*)&o2e[row * 24 + cib];
                acc = __builtin_amdgcn_mfma_f32_16x16x32_bf16(a.b, b3f[kb].b, acc, 0, 0, 0);
            }
            const int tD = t0 + 4 * g;
            #pragma unroll
            for (int r = 0; r < 4; ++r) {
                float v = acc[r]; v = fmaxf(v, 0.01f * v);
                outn[1536 + (tD + r) * 16 + co] = v;            // scale 2
            }
        }
    }
}

extern "C" void kernel_launch(void* const* d_in, const int* in_sizes, int n_in,
                              void* d_out, int out_size, void* d_ws, size_t ws_size,
                              hipStream_t stream) {
    const float* x  = (const float*)d_in[0];
    const float* w1 = (const float*)d_in[1];
    const float* b1 = (const float*)d_in[2];
    const float* w2 = (const float*)d_in[3];
    const float* b2 = (const float*)d_in[4];
    const float* w3 = (const float*)d_in[5];
    const float* b3 = (const float*)d_in[6];
    float* out = (float*)d_out;
    unsigned int* ws = (unsigned int*)d_ws;           // 2608 u32 = 10.4 KB

    wtrans_kernel<<<1, 256, 0, stream>>>(w1, b1, w2, b2, w3, b3, ws);
    itl_kernel<<<8192, 64, 0, stream>>>(x, ws, out);  // 1 row per wave
}